// Round 3
// baseline (997.472 us; speedup 1.0000x reference)
//
#include <hip/hip_runtime.h>
#include <hip/hip_bf16.h>
#include <stdint.h>

#define TS 524288u
#define TMASK (TS - 1u)

__constant__ float c_NLf[16] = {16.f,22.f,30.f,42.f,58.f,80.f,111.f,153.f,
                                212.f,293.f,406.f,561.f,775.f,1071.f,1481.f,2046.f};

// ---------------------------------------------------------------------------
// K1: hash-grid encode. One thread per (point, level). tid = p*16 + l.
// 16M tiny threads, ~8 independent gathers each, low VGPR -> max occupancy ->
// high memory-level parallelism (the monolithic kernel had ~8 outstanding
// gathers per wave; this has ~64 per SIMD).
// Writes feats[p][32] as bf16 to workspace (feats are O(1e-4); bf16 rounding
// is ~1e-6 absolute -> negligible downstream).
// Outside-the-box points: skipped (K2 masks them and never reads their row).
// ---------------------------------------------------------------------------
__global__ __launch_bounds__(256)
void ngp_encode(const float* __restrict__ xg, const float* __restrict__ tables,
                __hip_bfloat16* __restrict__ feats, int n)
{
    const int tid = blockIdx.x * blockDim.x + threadIdx.x;
    const int p = tid >> 4;
    const int l = tid & 15;
    if (p >= n) return;

    const float px = xg[3*p+0], py = xg[3*p+1], pz = xg[3*p+2];
    float sx = px / 3.0f, sy = py / 3.0f, sz = pz / 3.0f;
    if (!((fabsf(sx) < 0.5f) && (fabsf(sy) < 0.5f) && (fabsf(sz) < 0.5f))) return;
    sx = fminf(fmaxf(sx + 0.5f, 0.0f), 1.0f);
    sy = fminf(fmaxf(sy + 0.5f, 0.0f), 1.0f);
    sz = fminf(fmaxf(sz + 0.5f, 0.0f), 1.0f);

    const float nf = c_NLf[l];
    const float xn0 = sx * nf, xn1 = sy * nf, xn2 = sz * nf;
    const float fl0 = floorf(xn0), fl1 = floorf(xn1), fl2 = floorf(xn2);
    const float w0 = xn0 - fl0, w1 = xn1 - fl1, w2 = xn2 - fl2;
    const uint32_t f0 = (uint32_t)fl0, f1 = (uint32_t)fl1, f2 = (uint32_t)fl2;
    const uint32_t c0 = (uint32_t)ceilf(xn0);
    const uint32_t c1 = (uint32_t)ceilf(xn1);
    const uint32_t c2 = (uint32_t)ceilf(xn2);

    const uint32_t hyf = f1 * 2654435761u, hyc = c1 * 2654435761u;
    const uint32_t hzf = f2 * 805459861u,  hzc = c2 * 805459861u;
    const float* tb = tables + (size_t)l * (size_t)(TS * 2u);

    // 8 independent gathers
    const float2 v0 = *reinterpret_cast<const float2*>(tb + 2u*((f0 ^ hyf ^ hzf) & TMASK));
    const float2 v1 = *reinterpret_cast<const float2*>(tb + 2u*((c0 ^ hyf ^ hzf) & TMASK));
    const float2 v2 = *reinterpret_cast<const float2*>(tb + 2u*((f0 ^ hyc ^ hzf) & TMASK));
    const float2 v3 = *reinterpret_cast<const float2*>(tb + 2u*((c0 ^ hyc ^ hzf) & TMASK));
    const float2 v4 = *reinterpret_cast<const float2*>(tb + 2u*((f0 ^ hyf ^ hzc) & TMASK));
    const float2 v5 = *reinterpret_cast<const float2*>(tb + 2u*((c0 ^ hyf ^ hzc) & TMASK));
    const float2 v6 = *reinterpret_cast<const float2*>(tb + 2u*((f0 ^ hyc ^ hzc) & TMASK));
    const float2 v7 = *reinterpret_cast<const float2*>(tb + 2u*((c0 ^ hyc ^ hzc) & TMASK));

    const float u0 = 1.0f - w0, u1 = 1.0f - w1, u2 = 1.0f - w2;
    float a0, a1;
    a0 = u0*u1*u2 * v0.x;              a1 = u0*u1*u2 * v0.y;
    a0 = fmaf(w0*u1*u2, v1.x, a0);     a1 = fmaf(w0*u1*u2, v1.y, a1);
    a0 = fmaf(u0*w1*u2, v2.x, a0);     a1 = fmaf(u0*w1*u2, v2.y, a1);
    a0 = fmaf(w0*w1*u2, v3.x, a0);     a1 = fmaf(w0*w1*u2, v3.y, a1);
    a0 = fmaf(u0*u1*w2, v4.x, a0);     a1 = fmaf(u0*u1*w2, v4.y, a1);
    a0 = fmaf(w0*u1*w2, v5.x, a0);     a1 = fmaf(w0*u1*w2, v5.y, a1);
    a0 = fmaf(u0*w1*w2, v6.x, a0);     a1 = fmaf(u0*w1*w2, v6.y, a1);
    a0 = fmaf(w0*w1*w2, v7.x, a0);     a1 = fmaf(w0*w1*w2, v7.y, a1);

    __hip_bfloat162 pk;
    pk.x = __float2bfloat16(a0);
    pk.y = __float2bfloat16(a1);
    *reinterpret_cast<__hip_bfloat162*>(feats + (size_t)p*32 + 2*l) = pk;
}

// ---------------------------------------------------------------------------
// K2: MLPs. One thread per point, pure f32 FMA, no gathers. With the encode
// phase removed, resident waves (7+/EU at ~68 VGPR) hide the FMA-chain
// latency and the VALU should saturate.
// ---------------------------------------------------------------------------
__global__ __launch_bounds__(256)
void ngp_mlp(const float* __restrict__ xg, const float* __restrict__ dg,
             const __hip_bfloat16* __restrict__ feats_ws,
             const float* __restrict__ dW1, const float* __restrict__ db1,
             const float* __restrict__ dW2, const float* __restrict__ db2,
             const float* __restrict__ cW1, const float* __restrict__ cb1,
             const float* __restrict__ cW2, const float* __restrict__ cb2,
             const float* __restrict__ cW3, const float* __restrict__ cb3,
             float* __restrict__ out, int n)
{
    const int tid = blockIdx.x * blockDim.x + threadIdx.x;
    if (tid >= n) return;

    const float px = xg[3*tid+0], py = xg[3*tid+1], pz = xg[3*tid+2];
    const float sx = px / 3.0f, sy = py / 3.0f, sz = pz / 3.0f;
    if (!((fabsf(sx) < 0.5f) && (fabsf(sy) < 0.5f) && (fabsf(sz) < 0.5f))) {
        out[3*tid+0] = 0.0f; out[3*tid+1] = 0.0f; out[3*tid+2] = 0.0f;
        out[(size_t)3*n + tid] = 0.0f;   // exp(-10000) == 0
        return;
    }

    // load feats row: 64 B = 4x 16-B loads, unpack bf16 pairs
    float feats[32];
    {
        const uint4* fp = reinterpret_cast<const uint4*>(feats_ws + (size_t)tid*32);
        #pragma unroll
        for (int q = 0; q < 4; ++q) {
            const uint4 u = fp[q];
            const uint32_t uu[4] = {u.x, u.y, u.z, u.w};
            #pragma unroll
            for (int e = 0; e < 4; ++e) {
                feats[q*8 + 2*e + 0] = __uint_as_float(uu[e] << 16);
                feats[q*8 + 2*e + 1] = __uint_as_float(uu[e] & 0xffff0000u);
            }
        }
    }

    // density MLP: 32 -> 64 (relu) -> 16
    float hid[64];
    #pragma unroll
    for (int j = 0; j < 64; ++j) hid[j] = db1[j];
    #pragma unroll
    for (int k = 0; k < 32; ++k) {
        const float xv = feats[k];
        #pragma unroll
        for (int j = 0; j < 64; ++j) hid[j] = fmaf(xv, dW1[k*64+j], hid[j]);
    }
    #pragma unroll
    for (int j = 0; j < 64; ++j) hid[j] = fmaxf(hid[j], 0.0f);

    float h16[16];
    #pragma unroll
    for (int j = 0; j < 16; ++j) h16[j] = db2[j];
    #pragma unroll
    for (int k = 0; k < 64; ++k) {
        const float xv = hid[k];
        #pragma unroll
        for (int j = 0; j < 16; ++j) h16[j] = fmaf(xv, dW2[k*16+j], h16[j]);
    }

    out[(size_t)3*n + tid] = __expf(h16[0]);

    // color input: [h16 (16), pos_enc(d) (27)]
    const float dx = dg[3*tid+0], dy = dg[3*tid+1], dz = dg[3*tid+2];
    float cin[43];
    #pragma unroll
    for (int j = 0; j < 16; ++j) cin[j] = h16[j];
    cin[16] = dx; cin[17] = dy; cin[18] = dz;
    #pragma unroll
    for (int f = 0; f < 4; ++f) {
        const float s = (float)(1 << f);
        cin[19 + 6*f + 0] = __sinf(s * dx);
        cin[19 + 6*f + 1] = __sinf(s * dy);
        cin[19 + 6*f + 2] = __sinf(s * dz);
        cin[22 + 6*f + 0] = __cosf(s * dx);
        cin[22 + 6*f + 1] = __cosf(s * dy);
        cin[22 + 6*f + 2] = __cosf(s * dz);
    }

    // color MLP: 43 -> 64 (relu) -> 64 (relu) -> 3 (sigmoid)
    float c1[64];
    #pragma unroll
    for (int j = 0; j < 64; ++j) c1[j] = cb1[j];
    #pragma unroll
    for (int k = 0; k < 43; ++k) {
        const float xv = cin[k];
        #pragma unroll
        for (int j = 0; j < 64; ++j) c1[j] = fmaf(xv, cW1[k*64+j], c1[j]);
    }
    #pragma unroll
    for (int j = 0; j < 64; ++j) c1[j] = fmaxf(c1[j], 0.0f);

    float c2[64];
    #pragma unroll
    for (int j = 0; j < 64; ++j) c2[j] = cb2[j];
    #pragma unroll
    for (int k = 0; k < 64; ++k) {
        const float xv = c1[k];
        #pragma unroll
        for (int j = 0; j < 64; ++j) c2[j] = fmaf(xv, cW2[k*64+j], c2[j]);
    }
    #pragma unroll
    for (int j = 0; j < 64; ++j) c2[j] = fmaxf(c2[j], 0.0f);

    float c3[3];
    #pragma unroll
    for (int j = 0; j < 3; ++j) c3[j] = cb3[j];
    #pragma unroll
    for (int k = 0; k < 64; ++k) {
        const float xv = c2[k];
        #pragma unroll
        for (int j = 0; j < 3; ++j) c3[j] = fmaf(xv, cW3[k*3+j], c3[j]);
    }
    #pragma unroll
    for (int j = 0; j < 3; ++j) {
        out[3*tid+j] = 1.0f / (1.0f + __expf(-c3[j]));
    }
}

extern "C" void kernel_launch(void* const* d_in, const int* in_sizes, int n_in,
                              void* d_out, int out_size, void* d_ws, size_t ws_size,
                              hipStream_t stream)
{
    const float* x   = (const float*)d_in[0];
    const float* d   = (const float*)d_in[1];
    const float* tb  = (const float*)d_in[2];
    const float* dW1 = (const float*)d_in[3];
    const float* db1 = (const float*)d_in[4];
    const float* dW2 = (const float*)d_in[5];
    const float* db2 = (const float*)d_in[6];
    const float* cW1 = (const float*)d_in[7];
    const float* cb1 = (const float*)d_in[8];
    const float* cW2 = (const float*)d_in[9];
    const float* cb2 = (const float*)d_in[10];
    const float* cW3 = (const float*)d_in[11];
    const float* cb3 = (const float*)d_in[12];
    float* out = (float*)d_out;

    const int n = in_sizes[0] / 3;  // N_PTS = 1M
    __hip_bfloat16* feats = (__hip_bfloat16*)d_ws;  // [n][32] bf16 = 64 MB

    {
        const long long threads = (long long)n * 16;
        dim3 block(256);
        dim3 grid((unsigned)((threads + 255) / 256));
        hipLaunchKernelGGL(ngp_encode, grid, block, 0, stream, x, tb, feats, n);
    }
    {
        dim3 block(256);
        dim3 grid((n + 255) / 256);
        hipLaunchKernelGGL(ngp_mlp, grid, block, 0, stream,
                           x, d, feats, dW1, db1, dW2, db2,
                           cW1, cb1, cW2, cb2, cW3, cb3, out, n);
    }
}

// Round 4
// 780.856 us; speedup vs baseline: 1.2774x; 1.2774x over previous
//
#include <hip/hip_runtime.h>
#include <hip/hip_bf16.h>
#include <stdint.h>

#define TS 524288u
#define TMASK (TS - 1u)

typedef __attribute__((ext_vector_type(8))) short bf16x8;
typedef __attribute__((ext_vector_type(4))) short short4v;
typedef __attribute__((ext_vector_type(4))) float f32x4;

__device__ __forceinline__ short f2bf(float f) {
    union { float f; uint32_t u; } v; v.f = f;
    const uint32_t r = (v.u + 0x7fffu + ((v.u >> 16) & 1u)) >> 16;  // RNE
    return (short)r;
}

__constant__ float c_NLf[16] = {16.f,22.f,30.f,42.f,58.f,80.f,111.f,153.f,
                                212.f,293.f,406.f,561.f,775.f,1071.f,1481.f,2046.f};

// ---------------------------------------------------------------------------
// K1: hash-grid encode. grid = (ceil(n/256), 16 levels). A wave = 64
// consecutive points at ONE level (uniform table -> better coarse-level
// coalescing than R3's point-major interleave). Writes feats[p][32] bf16.
// Outside-the-box points get zeros (K2 computes all rows, masks at output).
// ---------------------------------------------------------------------------
__global__ __launch_bounds__(256)
void ngp_encode(const float* __restrict__ xg, const float* __restrict__ tables,
                short* __restrict__ feats, int n)
{
    const int p = blockIdx.x * blockDim.x + threadIdx.x;
    const int l = blockIdx.y;
    if (p >= n) return;

    const float px = xg[3*p+0], py = xg[3*p+1], pz = xg[3*p+2];
    float sx = px / 3.0f, sy = py / 3.0f, sz = pz / 3.0f;
    if (!((fabsf(sx) < 0.5f) && (fabsf(sy) < 0.5f) && (fabsf(sz) < 0.5f))) {
        *reinterpret_cast<int*>(feats + (size_t)p*32 + 2*l) = 0;
        return;
    }
    sx = fminf(fmaxf(sx + 0.5f, 0.0f), 1.0f);
    sy = fminf(fmaxf(sy + 0.5f, 0.0f), 1.0f);
    sz = fminf(fmaxf(sz + 0.5f, 0.0f), 1.0f);

    const float nf = c_NLf[l];
    const float xn0 = sx * nf, xn1 = sy * nf, xn2 = sz * nf;
    const float fl0 = floorf(xn0), fl1 = floorf(xn1), fl2 = floorf(xn2);
    const float w0 = xn0 - fl0, w1 = xn1 - fl1, w2 = xn2 - fl2;
    const uint32_t f0 = (uint32_t)fl0, f1 = (uint32_t)fl1, f2 = (uint32_t)fl2;
    const uint32_t c0 = (uint32_t)ceilf(xn0);
    const uint32_t c1 = (uint32_t)ceilf(xn1);
    const uint32_t c2 = (uint32_t)ceilf(xn2);

    const uint32_t hyf = f1 * 2654435761u, hyc = c1 * 2654435761u;
    const uint32_t hzf = f2 * 805459861u,  hzc = c2 * 805459861u;
    const float* tb = tables + (size_t)l * (size_t)(TS * 2u);

    const float2 v0 = *reinterpret_cast<const float2*>(tb + 2u*((f0 ^ hyf ^ hzf) & TMASK));
    const float2 v1 = *reinterpret_cast<const float2*>(tb + 2u*((c0 ^ hyf ^ hzf) & TMASK));
    const float2 v2 = *reinterpret_cast<const float2*>(tb + 2u*((f0 ^ hyc ^ hzf) & TMASK));
    const float2 v3 = *reinterpret_cast<const float2*>(tb + 2u*((c0 ^ hyc ^ hzf) & TMASK));
    const float2 v4 = *reinterpret_cast<const float2*>(tb + 2u*((f0 ^ hyf ^ hzc) & TMASK));
    const float2 v5 = *reinterpret_cast<const float2*>(tb + 2u*((c0 ^ hyf ^ hzc) & TMASK));
    const float2 v6 = *reinterpret_cast<const float2*>(tb + 2u*((f0 ^ hyc ^ hzc) & TMASK));
    const float2 v7 = *reinterpret_cast<const float2*>(tb + 2u*((c0 ^ hyc ^ hzc) & TMASK));

    const float u0 = 1.0f - w0, u1 = 1.0f - w1, u2 = 1.0f - w2;
    float a0, a1;
    a0 = u0*u1*u2 * v0.x;              a1 = u0*u1*u2 * v0.y;
    a0 = fmaf(w0*u1*u2, v1.x, a0);     a1 = fmaf(w0*u1*u2, v1.y, a1);
    a0 = fmaf(u0*w1*u2, v2.x, a0);     a1 = fmaf(u0*w1*u2, v2.y, a1);
    a0 = fmaf(w0*w1*u2, v3.x, a0);     a1 = fmaf(w0*w1*u2, v3.y, a1);
    a0 = fmaf(u0*u1*w2, v4.x, a0);     a1 = fmaf(u0*u1*w2, v4.y, a1);
    a0 = fmaf(w0*u1*w2, v5.x, a0);     a1 = fmaf(w0*u1*w2, v5.y, a1);
    a0 = fmaf(u0*w1*w2, v6.x, a0);     a1 = fmaf(u0*w1*w2, v6.y, a1);
    a0 = fmaf(w0*w1*w2, v7.x, a0);     a1 = fmaf(w0*w1*w2, v7.y, a1);

    const uint32_t pk = (uint32_t)(uint16_t)f2bf(a0) | ((uint32_t)(uint16_t)f2bf(a1) << 16);
    *reinterpret_cast<uint32_t*>(feats + (size_t)p*32 + 2*l) = pk;
}

// ---------------------------------------------------------------------------
// K2: MFMA MLP. 1 block = 256 thr = 4 waves; 1 wave = 16 points.
// GEMM orientation per mfma_f32_16x16x32_bf16 layouts (learn_hip m89/m120):
//   A-frag (weightsT): A[m=lane&15][k=(lane>>4)*8+e]  -> m = out-feature j
//   B-frag (acts):     B[n=lane&15][k=(lane>>4)*8+e]  -> n = point p
//   C/D:               col(n)=lane&15, row(m)=(lane>>4)*4+reg
// Weights prepacked to LDS in A-frag order once per block; activations
// round-trip LDS (ping-pong buffers) between layers to re-enter B-frag order.
// ---------------------------------------------------------------------------
__global__ __launch_bounds__(256)
void ngp_mlp_mfma(const float* __restrict__ xg, const float* __restrict__ dg,
                  const short* __restrict__ feats,
                  const float* __restrict__ dW1, const float* __restrict__ db1,
                  const float* __restrict__ dW2, const float* __restrict__ db2,
                  const float* __restrict__ cW1, const float* __restrict__ cb1,
                  const float* __restrict__ cW2, const float* __restrict__ cb2,
                  const float* __restrict__ cW3, const float* __restrict__ cb3,
                  float* __restrict__ out, int n)
{
    __shared__ __align__(16) short w1[2048];   // [jb4][lane64][e8]          L1: 32->64
    __shared__ __align__(16) short w2[1024];   // [kb2][lane64][e8]          L2: 64->16
    __shared__ __align__(16) short w3[4096];   // [jb4][kb2][lane64][e8]     L3: 64(pad43)->64
    __shared__ __align__(16) short w4[4096];   // [jb4][kb2][lane64][e8]     L4: 64->64
    __shared__ __align__(16) short w5[1024];   // [kb2][lane64][e8]          L5: 64->16(3 used)
    __shared__ float b1[64], b2[16], b3[64], b4[64], b5[16];
    __shared__ __align__(16) short act[2][4][16*64];  // [buf][wave][p*64+k]

    const int tid = threadIdx.x;

    // ---- prepack weights (f32 global -> bf16 LDS, A-frag order) ----
    for (int idx = tid; idx < 2048; idx += 256) {
        const int jb = idx >> 9, lane = (idx >> 3) & 63, e = idx & 7;
        const int j = jb*16 + (lane & 15), k = ((lane >> 4) << 3) + e;   // k<32
        w1[idx] = f2bf(dW1[k*64 + j]);
    }
    for (int idx = tid; idx < 1024; idx += 256) {
        const int kb = idx >> 9, lane = (idx >> 3) & 63, e = idx & 7;
        const int j = lane & 15, k = kb*32 + ((lane >> 4) << 3) + e;     // k<64
        w2[idx] = f2bf(dW2[k*16 + j]);
    }
    for (int idx = tid; idx < 4096; idx += 256) {
        const int jb = idx >> 10, kb = (idx >> 9) & 1, lane = (idx >> 3) & 63, e = idx & 7;
        const int j = jb*16 + (lane & 15), k = kb*32 + ((lane >> 4) << 3) + e;
        w3[idx] = (k < 43) ? f2bf(cW1[k*64 + j]) : (short)0;
        w4[idx] = f2bf(cW2[k*64 + j]);
    }
    for (int idx = tid; idx < 1024; idx += 256) {
        const int kb = idx >> 9, lane = (idx >> 3) & 63, e = idx & 7;
        const int j = lane & 15, k = kb*32 + ((lane >> 4) << 3) + e;
        w5[idx] = (j < 3) ? f2bf(cW3[k*3 + j]) : (short)0;
    }
    if (tid < 64) { b1[tid] = db1[tid]; b3[tid] = cb1[tid]; b4[tid] = cb2[tid]; }
    if (tid < 16) { b2[tid] = db2[tid]; b5[tid] = (tid < 3) ? cb3[tid] : 0.0f; }
    __syncthreads();

    const int wv = tid >> 6, lane = tid & 63;
    const int p16 = lane & 15, quad = lane >> 4;
    const int pp_raw = (blockIdx.x*4 + wv)*16 + p16;
    const int pp = (pp_raw < n) ? pp_raw : (n - 1);
    const bool valid = (pp_raw < n);

    short* buf0 = &act[0][wv][0];
    short* buf1 = &act[1][wv][0];

    // mask (reference box test, exact ops)
    const float mx = xg[3*pp+0] / 3.0f, my = xg[3*pp+1] / 3.0f, mz = xg[3*pp+2] / 3.0f;
    const bool inside = (fabsf(mx) < 0.5f) && (fabsf(my) < 0.5f) && (fabsf(mz) < 0.5f);

    // ---- L1: feats[32] -> hid[64], relu ----
    const bf16x8 bA = *reinterpret_cast<const bf16x8*>(feats + (size_t)pp*32 + quad*8);
    #pragma unroll
    for (int jb = 0; jb < 4; ++jb) {
        const int j0 = jb*16 + quad*4;
        f32x4 acc = { b1[j0], b1[j0+1], b1[j0+2], b1[j0+3] };
        const bf16x8 aF = *reinterpret_cast<const bf16x8*>(&w1[(jb*64 + lane)*8]);
        acc = __builtin_amdgcn_mfma_f32_16x16x32_bf16(aF, bA, acc, 0, 0, 0);
        short4v s;
        s[0] = f2bf(fmaxf(acc[0], 0.f)); s[1] = f2bf(fmaxf(acc[1], 0.f));
        s[2] = f2bf(fmaxf(acc[2], 0.f)); s[3] = f2bf(fmaxf(acc[3], 0.f));
        *reinterpret_cast<short4v*>(&buf0[p16*64 + j0]) = s;
    }
    __syncthreads();

    // ---- L2: hid[64] -> h16[16] (no relu) ----
    f32x4 acc2 = { b2[quad*4], b2[quad*4+1], b2[quad*4+2], b2[quad*4+3] };
    #pragma unroll
    for (int kb = 0; kb < 2; ++kb) {
        const bf16x8 bF = *reinterpret_cast<const bf16x8*>(&buf0[p16*64 + kb*32 + quad*8]);
        const bf16x8 aF = *reinterpret_cast<const bf16x8*>(&w2[(kb*64 + lane)*8]);
        acc2 = __builtin_amdgcn_mfma_f32_16x16x32_bf16(aF, bF, acc2, 0, 0, 0);
    }
    // sigma from f32 accumulator (row j=0 lives in quad 0, reg 0)
    if (quad == 0 && valid)
        out[(size_t)3*n + pp] = inside ? __expf(acc2[0]) : 0.0f;
    {   // h16 -> buf1[p][0..15]
        short4v s;
        s[0] = f2bf(acc2[0]); s[1] = f2bf(acc2[1]);
        s[2] = f2bf(acc2[2]); s[3] = f2bf(acc2[3]);
        *reinterpret_cast<short4v*>(&buf1[p16*64 + quad*4]) = s;
    }
    // pos-enc -> buf1[p][16..42], zeros [43..63]; quads stride the index
    {
        const float d0 = dg[3*pp+0], d1 = dg[3*pp+1], d2 = dg[3*pp+2];
        for (int idx = 16 + quad; idx < 64; idx += 4) {
            float val = 0.0f;
            if (idx < 19) {
                val = (idx == 16) ? d0 : ((idx == 17) ? d1 : d2);
            } else if (idx < 43) {
                const int g = idx - 19, f = g / 6, rem = g - 6*f;
                const int c = (rem < 3) ? rem : rem - 3;
                const float arg = ((c == 0) ? d0 : ((c == 1) ? d1 : d2)) * (float)(1 << f);
                val = (rem < 3) ? __sinf(arg) : __cosf(arg);
            }
            buf1[p16*64 + idx] = f2bf(val);
        }
    }
    __syncthreads();

    // ---- L3: cin[64(pad)] -> c1[64], relu ----
    #pragma unroll
    for (int jb = 0; jb < 4; ++jb) {
        const int j0 = jb*16 + quad*4;
        f32x4 acc = { b3[j0], b3[j0+1], b3[j0+2], b3[j0+3] };
        #pragma unroll
        for (int kb = 0; kb < 2; ++kb) {
            const bf16x8 bF = *reinterpret_cast<const bf16x8*>(&buf1[p16*64 + kb*32 + quad*8]);
            const bf16x8 aF = *reinterpret_cast<const bf16x8*>(&w3[((jb*2 + kb)*64 + lane)*8]);
            acc = __builtin_amdgcn_mfma_f32_16x16x32_bf16(aF, bF, acc, 0, 0, 0);
        }
        short4v s;
        s[0] = f2bf(fmaxf(acc[0], 0.f)); s[1] = f2bf(fmaxf(acc[1], 0.f));
        s[2] = f2bf(fmaxf(acc[2], 0.f)); s[3] = f2bf(fmaxf(acc[3], 0.f));
        *reinterpret_cast<short4v*>(&buf0[p16*64 + j0]) = s;
    }
    __syncthreads();

    // ---- L4: c1[64] -> c2[64], relu ----
    #pragma unroll
    for (int jb = 0; jb < 4; ++jb) {
        const int j0 = jb*16 + quad*4;
        f32x4 acc = { b4[j0], b4[j0+1], b4[j0+2], b4[j0+3] };
        #pragma unroll
        for (int kb = 0; kb < 2; ++kb) {
            const bf16x8 bF = *reinterpret_cast<const bf16x8*>(&buf0[p16*64 + kb*32 + quad*8]);
            const bf16x8 aF = *reinterpret_cast<const bf16x8*>(&w4[((jb*2 + kb)*64 + lane)*8]);
            acc = __builtin_amdgcn_mfma_f32_16x16x32_bf16(aF, bF, acc, 0, 0, 0);
        }
        short4v s;
        s[0] = f2bf(fmaxf(acc[0], 0.f)); s[1] = f2bf(fmaxf(acc[1], 0.f));
        s[2] = f2bf(fmaxf(acc[2], 0.f)); s[3] = f2bf(fmaxf(acc[3], 0.f));
        *reinterpret_cast<short4v*>(&buf1[p16*64 + j0]) = s;
    }
    __syncthreads();

    // ---- L5: c2[64] -> 16 (3 used), sigmoid, masked store ----
    f32x4 acc5 = { b5[quad*4], b5[quad*4+1], b5[quad*4+2], b5[quad*4+3] };
    #pragma unroll
    for (int kb = 0; kb < 2; ++kb) {
        const bf16x8 bF = *reinterpret_cast<const bf16x8*>(&buf1[p16*64 + kb*32 + quad*8]);
        const bf16x8 aF = *reinterpret_cast<const bf16x8*>(&w5[(kb*64 + lane)*8]);
        acc5 = __builtin_amdgcn_mfma_f32_16x16x32_bf16(aF, bF, acc5, 0, 0, 0);
    }
    if (quad == 0 && valid) {
        #pragma unroll
        for (int r = 0; r < 3; ++r) {
            const float s = 1.0f / (1.0f + __expf(-acc5[r]));
            out[3*pp + r] = inside ? s : 0.0f;
        }
    }
}

extern "C" void kernel_launch(void* const* d_in, const int* in_sizes, int n_in,
                              void* d_out, int out_size, void* d_ws, size_t ws_size,
                              hipStream_t stream)
{
    const float* x   = (const float*)d_in[0];
    const float* d   = (const float*)d_in[1];
    const float* tb  = (const float*)d_in[2];
    const float* dW1 = (const float*)d_in[3];
    const float* db1 = (const float*)d_in[4];
    const float* dW2 = (const float*)d_in[5];
    const float* db2 = (const float*)d_in[6];
    const float* cW1 = (const float*)d_in[7];
    const float* cb1 = (const float*)d_in[8];
    const float* cW2 = (const float*)d_in[9];
    const float* cb2 = (const float*)d_in[10];
    const float* cW3 = (const float*)d_in[11];
    const float* cb3 = (const float*)d_in[12];
    float* out = (float*)d_out;

    const int n = in_sizes[0] / 3;          // N_PTS = 1M
    short* feats = (short*)d_ws;            // [n][32] bf16 = 64 MB

    {
        dim3 block(256);
        dim3 grid((n + 255) / 256, 16);
        hipLaunchKernelGGL(ngp_encode, grid, block, 0, stream, x, tb, feats, n);
    }
    {
        dim3 block(256);
        dim3 grid((n + 63) / 64);           // 4 waves/block x 16 pts/wave
        hipLaunchKernelGGL(ngp_mlp_mfma, grid, block, 0, stream,
                           x, d, feats, dW1, db1, dW2, db2,
                           cW1, cb1, cW2, cb2, cW3, cb3, out, n);
    }
}

// Round 5
// 571.083 us; speedup vs baseline: 1.7466x; 1.3673x over previous
//
#include <hip/hip_runtime.h>
#include <hip/hip_bf16.h>
#include <stdint.h>

#define TS 524288u
#define TMASK (TS - 1u)

typedef __attribute__((ext_vector_type(8))) short bf16x8;
typedef __attribute__((ext_vector_type(4))) short short4v;
typedef __attribute__((ext_vector_type(4))) float f32x4;

__device__ __forceinline__ short f2bf(float f) {
    union { float f; uint32_t u; } v; v.f = f;
    const uint32_t r = (v.u + 0x7fffu + ((v.u >> 16) & 1u)) >> 16;  // RNE
    return (short)r;
}
__device__ __forceinline__ float bflo(uint32_t u) { return __uint_as_float(u << 16); }
__device__ __forceinline__ float bfhi(uint32_t u) { return __uint_as_float(u & 0xffff0000u); }

__constant__ float c_NLf[16] = {16.f,22.f,30.f,42.f,58.f,80.f,111.f,153.f,
                                212.f,293.f,406.f,561.f,775.f,1071.f,1481.f,2046.f};

// ---------------------------------------------------------------------------
// K0: convert f32 tables -> packed bf16 (dword = [f1|f0]) in workspace.
// Halves table bytes (64->32 MB): 2 levels fit one XCD L2 (4 MiB), and each
// 64-B line holds 16 entries (vs 8) -> less line amplification per gather.
// ---------------------------------------------------------------------------
__global__ __launch_bounds__(256)
void cvt_tables(const float2* __restrict__ src, uint32_t* __restrict__ dst, int npairs)
{
    const int i = blockIdx.x * 256 + threadIdx.x;
    if (i >= npairs) return;
    const float2 v = src[i];
    dst[i] = (uint32_t)(uint16_t)f2bf(v.x) | ((uint32_t)(uint16_t)f2bf(v.y) << 16);
}

// ---------------------------------------------------------------------------
// K1: hash-grid encode. Flattened grid: level = blockIdx.x & 15 so, with
// round-robin block->XCD dispatch, XCD k serves only levels {k, k+8} ->
// per-XCD table working set <= 4 MiB ~= its L2 (perf heuristic only).
// Output layout is LEVEL-MAJOR planes feats[l][p] (one dword per point-level):
// writes are fully coalesced (R4's point-major 4-B stride-64B writes caused
// 500 MB of write-allocate RMW on a 64 MB array).
// ---------------------------------------------------------------------------
template<bool PACKED>
__global__ __launch_bounds__(256)
void ngp_encode(const float* __restrict__ xg, const void* __restrict__ tables,
                uint32_t* __restrict__ feats_lm, int n)
{
    const int b = blockIdx.x;
    const int l = b & 15;
    const int p = (b >> 4) * 256 + threadIdx.x;
    if (p >= n) return;

    const float px = xg[3*p+0], py = xg[3*p+1], pz = xg[3*p+2];
    float sx = px / 3.0f, sy = py / 3.0f, sz = pz / 3.0f;
    if (!((fabsf(sx) < 0.5f) && (fabsf(sy) < 0.5f) && (fabsf(sz) < 0.5f))) {
        feats_lm[(size_t)l * n + p] = 0u;
        return;
    }
    sx = fminf(fmaxf(sx + 0.5f, 0.0f), 1.0f);
    sy = fminf(fmaxf(sy + 0.5f, 0.0f), 1.0f);
    sz = fminf(fmaxf(sz + 0.5f, 0.0f), 1.0f);

    const float nf = c_NLf[l];
    const float xn0 = sx * nf, xn1 = sy * nf, xn2 = sz * nf;
    const float fl0 = floorf(xn0), fl1 = floorf(xn1), fl2 = floorf(xn2);
    const float w0 = xn0 - fl0, w1 = xn1 - fl1, w2 = xn2 - fl2;
    const uint32_t f0 = (uint32_t)fl0, f1 = (uint32_t)fl1, f2 = (uint32_t)fl2;
    const uint32_t c0 = (uint32_t)ceilf(xn0);
    const uint32_t c1 = (uint32_t)ceilf(xn1);
    const uint32_t c2 = (uint32_t)ceilf(xn2);

    const uint32_t hyf = f1 * 2654435761u, hyc = c1 * 2654435761u;
    const uint32_t hzf = f2 * 805459861u,  hzc = c2 * 805459861u;
    const uint32_t h0 = (f0 ^ hyf ^ hzf) & TMASK, h1 = (c0 ^ hyf ^ hzf) & TMASK;
    const uint32_t h2 = (f0 ^ hyc ^ hzf) & TMASK, h3 = (c0 ^ hyc ^ hzf) & TMASK;
    const uint32_t h4 = (f0 ^ hyf ^ hzc) & TMASK, h5 = (c0 ^ hyf ^ hzc) & TMASK;
    const uint32_t h6 = (f0 ^ hyc ^ hzc) & TMASK, h7 = (c0 ^ hyc ^ hzc) & TMASK;

    float v0x,v0y,v1x,v1y,v2x,v2y,v3x,v3y,v4x,v4y,v5x,v5y,v6x,v6y,v7x,v7y;
    if (PACKED) {
        const uint32_t* tb = (const uint32_t*)tables + (size_t)l * TS;
        const uint32_t e0 = tb[h0], e1 = tb[h1], e2 = tb[h2], e3 = tb[h3];
        const uint32_t e4 = tb[h4], e5 = tb[h5], e6 = tb[h6], e7 = tb[h7];
        v0x = bflo(e0); v0y = bfhi(e0); v1x = bflo(e1); v1y = bfhi(e1);
        v2x = bflo(e2); v2y = bfhi(e2); v3x = bflo(e3); v3y = bfhi(e3);
        v4x = bflo(e4); v4y = bfhi(e4); v5x = bflo(e5); v5y = bfhi(e5);
        v6x = bflo(e6); v6y = bfhi(e6); v7x = bflo(e7); v7y = bfhi(e7);
    } else {
        const float2* tb = (const float2*)tables + (size_t)l * TS;
        const float2 e0 = tb[h0], e1 = tb[h1], e2 = tb[h2], e3 = tb[h3];
        const float2 e4 = tb[h4], e5 = tb[h5], e6 = tb[h6], e7 = tb[h7];
        v0x = e0.x; v0y = e0.y; v1x = e1.x; v1y = e1.y;
        v2x = e2.x; v2y = e2.y; v3x = e3.x; v3y = e3.y;
        v4x = e4.x; v4y = e4.y; v5x = e5.x; v5y = e5.y;
        v6x = e6.x; v6y = e6.y; v7x = e7.x; v7y = e7.y;
    }

    const float u0 = 1.0f - w0, u1 = 1.0f - w1, u2 = 1.0f - w2;
    float a0, a1;
    a0 = u0*u1*u2 * v0x;              a1 = u0*u1*u2 * v0y;
    a0 = fmaf(w0*u1*u2, v1x, a0);     a1 = fmaf(w0*u1*u2, v1y, a1);
    a0 = fmaf(u0*w1*u2, v2x, a0);     a1 = fmaf(u0*w1*u2, v2y, a1);
    a0 = fmaf(w0*w1*u2, v3x, a0);     a1 = fmaf(w0*w1*u2, v3y, a1);
    a0 = fmaf(u0*u1*w2, v4x, a0);     a1 = fmaf(u0*u1*w2, v4y, a1);
    a0 = fmaf(w0*u1*w2, v5x, a0);     a1 = fmaf(w0*u1*w2, v5y, a1);
    a0 = fmaf(u0*w1*w2, v6x, a0);     a1 = fmaf(u0*w1*w2, v6y, a1);
    a0 = fmaf(w0*w1*w2, v7x, a0);     a1 = fmaf(w0*w1*w2, v7y, a1);

    feats_lm[(size_t)l * n + p] =
        (uint32_t)(uint16_t)f2bf(a0) | ((uint32_t)(uint16_t)f2bf(a1) << 16);
}

// ---------------------------------------------------------------------------
// K2: MFMA MLP, persistent grid-stride blocks (weight prepack amortized over
// ~20 point-tiles instead of paid per 64 points as in R4).
// Wave = 16 points. A-frag = weightsT in LDS, B-frag = activations.
// act rows padded 64->72 shorts: R4's 128-B stride was a 16-way LDS bank
// conflict on every fragment access; 144-B stride is 2-way (free, m136).
// ---------------------------------------------------------------------------
#define ACT_STRIDE 72

__global__ __launch_bounds__(256)
void ngp_mlp_mfma(const float* __restrict__ xg, const float* __restrict__ dg,
                  const uint32_t* __restrict__ feats_lm,
                  const float* __restrict__ dW1, const float* __restrict__ db1,
                  const float* __restrict__ dW2, const float* __restrict__ db2,
                  const float* __restrict__ cW1, const float* __restrict__ cb1,
                  const float* __restrict__ cW2, const float* __restrict__ cb2,
                  const float* __restrict__ cW3, const float* __restrict__ cb3,
                  float* __restrict__ out, int n)
{
    __shared__ __align__(16) short w1[2048];   // [jb4][lane64][e8]       L1: 32->64
    __shared__ __align__(16) short w2[1024];   // [kb2][lane64][e8]       L2: 64->16
    __shared__ __align__(16) short w3[4096];   // [jb4][kb2][lane64][e8]  L3: 64(pad43)->64
    __shared__ __align__(16) short w4[4096];   // [jb4][kb2][lane64][e8]  L4: 64->64
    __shared__ __align__(16) short w5[1024];   // [kb2][lane64][e8]       L5: 64->16(3 used)
    __shared__ float b1[64], b2[16], b3[64], b4[64], b5[16];
    __shared__ __align__(16) short act[2][4][16*ACT_STRIDE];

    const int tid = threadIdx.x;

    // ---- prepack weights (once per persistent block) ----
    for (int idx = tid; idx < 2048; idx += 256) {
        const int jb = idx >> 9, lane = (idx >> 3) & 63, e = idx & 7;
        const int j = jb*16 + (lane & 15), k = ((lane >> 4) << 3) + e;
        w1[idx] = f2bf(dW1[k*64 + j]);
    }
    for (int idx = tid; idx < 1024; idx += 256) {
        const int kb = idx >> 9, lane = (idx >> 3) & 63, e = idx & 7;
        const int j = lane & 15, k = kb*32 + ((lane >> 4) << 3) + e;
        w2[idx] = f2bf(dW2[k*16 + j]);
    }
    for (int idx = tid; idx < 4096; idx += 256) {
        const int jb = idx >> 10, kb = (idx >> 9) & 1, lane = (idx >> 3) & 63, e = idx & 7;
        const int j = jb*16 + (lane & 15), k = kb*32 + ((lane >> 4) << 3) + e;
        w3[idx] = (k < 43) ? f2bf(cW1[k*64 + j]) : (short)0;
        w4[idx] = f2bf(cW2[k*64 + j]);
    }
    for (int idx = tid; idx < 1024; idx += 256) {
        const int kb = idx >> 9, lane = (idx >> 3) & 63, e = idx & 7;
        const int j = lane & 15, k = kb*32 + ((lane >> 4) << 3) + e;
        w5[idx] = (j < 3) ? f2bf(cW3[k*3 + j]) : (short)0;
    }
    if (tid < 64) { b1[tid] = db1[tid]; b3[tid] = cb1[tid]; b4[tid] = cb2[tid]; }
    if (tid < 16) { b2[tid] = db2[tid]; b5[tid] = (tid < 3) ? cb3[tid] : 0.0f; }
    __syncthreads();

    const int wv = tid >> 6, lane = tid & 63;
    const int p16 = lane & 15, quad = lane >> 4;
    short* buf0 = &act[0][wv][0];
    short* buf1 = &act[1][wv][0];

    const int ntiles = (n + 63) >> 6;   // 64 points per block-tile
    for (int t = blockIdx.x; t < ntiles; t += gridDim.x) {
        const int pp_raw = t*64 + wv*16 + p16;
        const int pp = (pp_raw < n) ? pp_raw : (n - 1);
        const bool valid = (pp_raw < n);

        const float mx = xg[3*pp+0] / 3.0f, my = xg[3*pp+1] / 3.0f, mz = xg[3*pp+2] / 3.0f;
        const bool inside = (fabsf(mx) < 0.5f) && (fabsf(my) < 0.5f) && (fabsf(mz) < 0.5f);

        // ---- L1: feats[32] -> hid[64], relu.  B-frag k=quad*8+e -> levels 4q..4q+3
        union { int4 i; bf16x8 v; } bu;
        bu.i.x = (int)feats_lm[(size_t)(4*quad+0)*n + pp];
        bu.i.y = (int)feats_lm[(size_t)(4*quad+1)*n + pp];
        bu.i.z = (int)feats_lm[(size_t)(4*quad+2)*n + pp];
        bu.i.w = (int)feats_lm[(size_t)(4*quad+3)*n + pp];
        const bf16x8 bA = bu.v;
        #pragma unroll
        for (int jb = 0; jb < 4; ++jb) {
            const int j0 = jb*16 + quad*4;
            f32x4 acc = { b1[j0], b1[j0+1], b1[j0+2], b1[j0+3] };
            const bf16x8 aF = *reinterpret_cast<const bf16x8*>(&w1[(jb*64 + lane)*8]);
            acc = __builtin_amdgcn_mfma_f32_16x16x32_bf16(aF, bA, acc, 0, 0, 0);
            short4v s;
            s[0] = f2bf(fmaxf(acc[0], 0.f)); s[1] = f2bf(fmaxf(acc[1], 0.f));
            s[2] = f2bf(fmaxf(acc[2], 0.f)); s[3] = f2bf(fmaxf(acc[3], 0.f));
            *reinterpret_cast<short4v*>(&buf0[p16*ACT_STRIDE + j0]) = s;
        }
        __syncthreads();

        // ---- L2: hid[64] -> h16[16] (no relu) ----
        f32x4 acc2 = { b2[quad*4], b2[quad*4+1], b2[quad*4+2], b2[quad*4+3] };
        #pragma unroll
        for (int kb = 0; kb < 2; ++kb) {
            const bf16x8 bF = *reinterpret_cast<const bf16x8*>(&buf0[p16*ACT_STRIDE + kb*32 + quad*8]);
            const bf16x8 aF = *reinterpret_cast<const bf16x8*>(&w2[(kb*64 + lane)*8]);
            acc2 = __builtin_amdgcn_mfma_f32_16x16x32_bf16(aF, bF, acc2, 0, 0, 0);
        }
        if (quad == 0 && valid)
            out[(size_t)3*n + pp] = inside ? __expf(acc2[0]) : 0.0f;
        {
            short4v s;
            s[0] = f2bf(acc2[0]); s[1] = f2bf(acc2[1]);
            s[2] = f2bf(acc2[2]); s[3] = f2bf(acc2[3]);
            *reinterpret_cast<short4v*>(&buf1[p16*ACT_STRIDE + quad*4]) = s;
        }
        {   // pos-enc -> buf1[p][16..42], zeros [43..63]
            const float d0 = dg[3*pp+0], d1 = dg[3*pp+1], d2 = dg[3*pp+2];
            for (int idx = 16 + quad; idx < 64; idx += 4) {
                float val = 0.0f;
                if (idx < 19) {
                    val = (idx == 16) ? d0 : ((idx == 17) ? d1 : d2);
                } else if (idx < 43) {
                    const int g = idx - 19, f = g / 6, rem = g - 6*f;
                    const int c = (rem < 3) ? rem : rem - 3;
                    const float arg = ((c == 0) ? d0 : ((c == 1) ? d1 : d2)) * (float)(1 << f);
                    val = (rem < 3) ? __sinf(arg) : __cosf(arg);
                }
                buf1[p16*ACT_STRIDE + idx] = f2bf(val);
            }
        }
        __syncthreads();

        // ---- L3: cin[64(pad)] -> c1[64], relu ----
        #pragma unroll
        for (int jb = 0; jb < 4; ++jb) {
            const int j0 = jb*16 + quad*4;
            f32x4 acc = { b3[j0], b3[j0+1], b3[j0+2], b3[j0+3] };
            #pragma unroll
            for (int kb = 0; kb < 2; ++kb) {
                const bf16x8 bF = *reinterpret_cast<const bf16x8*>(&buf1[p16*ACT_STRIDE + kb*32 + quad*8]);
                const bf16x8 aF = *reinterpret_cast<const bf16x8*>(&w3[((jb*2 + kb)*64 + lane)*8]);
                acc = __builtin_amdgcn_mfma_f32_16x16x32_bf16(aF, bF, acc, 0, 0, 0);
            }
            short4v s;
            s[0] = f2bf(fmaxf(acc[0], 0.f)); s[1] = f2bf(fmaxf(acc[1], 0.f));
            s[2] = f2bf(fmaxf(acc[2], 0.f)); s[3] = f2bf(fmaxf(acc[3], 0.f));
            *reinterpret_cast<short4v*>(&buf0[p16*ACT_STRIDE + j0]) = s;
        }
        __syncthreads();

        // ---- L4: c1[64] -> c2[64], relu ----
        #pragma unroll
        for (int jb = 0; jb < 4; ++jb) {
            const int j0 = jb*16 + quad*4;
            f32x4 acc = { b4[j0], b4[j0+1], b4[j0+2], b4[j0+3] };
            #pragma unroll
            for (int kb = 0; kb < 2; ++kb) {
                const bf16x8 bF = *reinterpret_cast<const bf16x8*>(&buf0[p16*ACT_STRIDE + kb*32 + quad*8]);
                const bf16x8 aF = *reinterpret_cast<const bf16x8*>(&w4[((jb*2 + kb)*64 + lane)*8]);
                acc = __builtin_amdgcn_mfma_f32_16x16x32_bf16(aF, bF, acc, 0, 0, 0);
            }
            short4v s;
            s[0] = f2bf(fmaxf(acc[0], 0.f)); s[1] = f2bf(fmaxf(acc[1], 0.f));
            s[2] = f2bf(fmaxf(acc[2], 0.f)); s[3] = f2bf(fmaxf(acc[3], 0.f));
            *reinterpret_cast<short4v*>(&buf1[p16*ACT_STRIDE + j0]) = s;
        }
        __syncthreads();

        // ---- L5: c2[64] -> 16 (3 used), sigmoid, masked store ----
        f32x4 acc5 = { b5[quad*4], b5[quad*4+1], b5[quad*4+2], b5[quad*4+3] };
        #pragma unroll
        for (int kb = 0; kb < 2; ++kb) {
            const bf16x8 bF = *reinterpret_cast<const bf16x8*>(&buf1[p16*ACT_STRIDE + kb*32 + quad*8]);
            const bf16x8 aF = *reinterpret_cast<const bf16x8*>(&w5[(kb*64 + lane)*8]);
            acc5 = __builtin_amdgcn_mfma_f32_16x16x32_bf16(aF, bF, acc5, 0, 0, 0);
        }
        if (quad == 0 && valid) {
            #pragma unroll
            for (int r = 0; r < 3; ++r) {
                const float s = 1.0f / (1.0f + __expf(-acc5[r]));
                out[3*pp + r] = inside ? s : 0.0f;
            }
        }
        __syncthreads();   // protect act buffers before next tile
    }
}

extern "C" void kernel_launch(void* const* d_in, const int* in_sizes, int n_in,
                              void* d_out, int out_size, void* d_ws, size_t ws_size,
                              hipStream_t stream)
{
    const float* x   = (const float*)d_in[0];
    const float* d   = (const float*)d_in[1];
    const float* tb  = (const float*)d_in[2];
    const float* dW1 = (const float*)d_in[3];
    const float* db1 = (const float*)d_in[4];
    const float* dW2 = (const float*)d_in[5];
    const float* db2 = (const float*)d_in[6];
    const float* cW1 = (const float*)d_in[7];
    const float* cb1 = (const float*)d_in[8];
    const float* cW2 = (const float*)d_in[9];
    const float* cb2 = (const float*)d_in[10];
    const float* cW3 = (const float*)d_in[11];
    const float* cb3 = (const float*)d_in[12];
    float* out = (float*)d_out;

    const int n = in_sizes[0] / 3;              // N_PTS = 1M
    const size_t feats_bytes = (size_t)n * 16 * 4;          // level-major dword planes
    const size_t tb16_bytes  = (size_t)16 * TS * 4;         // packed bf16 tables
    uint32_t* feats_lm = (uint32_t*)d_ws;
    uint32_t* tb16     = (uint32_t*)((char*)d_ws + feats_bytes);
    const bool packed_ok = (ws_size >= feats_bytes + tb16_bytes);

    if (packed_ok) {
        const int npairs = 16 * (int)TS;
        dim3 block(256), grid((npairs + 255) / 256);
        hipLaunchKernelGGL(cvt_tables, grid, block, 0, stream,
                           (const float2*)tb, tb16, npairs);
    }
    {
        const int tiles = (n + 255) / 256;
        dim3 block(256), grid(tiles * 16);      // level = blockIdx.x & 15
        if (packed_ok)
            hipLaunchKernelGGL((ngp_encode<true>),  grid, block, 0, stream, x, (const void*)tb16, feats_lm, n);
        else
            hipLaunchKernelGGL((ngp_encode<false>), grid, block, 0, stream, x, (const void*)tb,   feats_lm, n);
    }
    {
        const int ntiles = (n + 63) >> 6;
        const int nblk = (ntiles < 768) ? ntiles : 768;
        dim3 block(256), grid(nblk);
        hipLaunchKernelGGL(ngp_mlp_mfma, grid, block, 0, stream,
                           x, d, feats_lm, dW1, db1, dW2, db2,
                           cW1, cb1, cW2, cb2, cW3, cb3, out, n);
    }
}